// Round 4
// baseline (268.652 us; speedup 1.0000x reference)
//
#include <hip/hip_runtime.h>

// Inverse 3D Haar (UnPatcher): in  [B=2, 8*G=128, T=8,  H=128, W=128] f32
//                              out [B=2,   G=16, 2T=16, 2H=256, 2W=256] f32
//
// out[b,g,2ti+pT,2hi+pH,2wi+pW] = (1/8) * sum_s (-1)^(bits(s)·(pT,pH,pW)) *
//                                 in[b, s*16+g, ti, hi, wi]
// where s = 4*tbit + 2*hbit + wbit (reference split order: lll,llh,lhl,...)
// and c^3 from the three synthesis stages times the 1/(2*sqrt(2)) rescale = 1/8.

typedef float f32x4 __attribute__((ext_vector_type(4)));  // native vec for nt-store

__device__ __forceinline__ float4 add4(float4 a, float4 b) {
    return make_float4(a.x + b.x, a.y + b.y, a.z + b.z, a.w + b.w);
}
__device__ __forceinline__ float4 sub4(float4 a, float4 b) {
    return make_float4(a.x - b.x, a.y - b.y, a.z - b.z, a.w - b.w);
}
__device__ __forceinline__ float4 scl4(float4 a, float s) {
    return make_float4(a.x * s, a.y * s, a.z * s, a.w * s);
}

__device__ __forceinline__ void nt_store4(float* p, float x, float y, float z, float w) {
    f32x4 v = {x, y, z, w};
    __builtin_nontemporal_store(v, reinterpret_cast<f32x4*>(p));
}

__global__ __launch_bounds__(256) void ihaar3d_kernel(const float* __restrict__ in,
                                                      float* __restrict__ out) {
    constexpr int TI = 8, HI = 128, WI = 128;   // input spatial dims
    constexpr int G  = 16;                      // output channels per batch
    constexpr int WQ = WI / 4;                  // 32 float4 per input W-row

    int idx = blockIdx.x * blockDim.x + threadIdx.x;
    const int wq = idx & (WQ - 1); idx >>= 5;   // float4 index along W_in
    const int hi = idx & (HI - 1); idx >>= 7;
    const int ti = idx & (TI - 1); idx >>= 3;
    const int g  = idx & (G  - 1); idx >>= 4;
    const int b  = idx;                         // 0..1

    // ---- gather the 8 subband float4s (all coalesced) ----
    const long inBase =
        (((long)(b * 128 + g) * TI + ti) * HI + hi) * WI + (long)wq * 4;
    const long sstride = (long)16 * TI * HI * WI;  // 16 channels * spatial

    float4 v[8];
#pragma unroll
    for (int s = 0; s < 8; ++s)
        v[s] = *reinterpret_cast<const float4*>(in + inBase + (long)s * sstride);

    // ---- 3-stage butterfly, all statically indexed (stays in VGPRs) ----
    // Stage W: A[tb][hb][pW]
    float4 A[2][2][2];
#pragma unroll
    for (int tb = 0; tb < 2; ++tb)
#pragma unroll
        for (int hb = 0; hb < 2; ++hb) {
            const float4 lo = v[4 * tb + 2 * hb + 0];
            const float4 hv = v[4 * tb + 2 * hb + 1];
            A[tb][hb][0] = add4(lo, hv);
            A[tb][hb][1] = sub4(lo, hv);
        }
    // Stage H: Bv[tb][pH][pW]
    float4 Bv[2][2][2];
#pragma unroll
    for (int tb = 0; tb < 2; ++tb)
#pragma unroll
        for (int pw = 0; pw < 2; ++pw) {
            Bv[tb][0][pw] = add4(A[tb][0][pw], A[tb][1][pw]);
            Bv[tb][1][pw] = sub4(A[tb][0][pw], A[tb][1][pw]);
        }
    // Stage T: Cv[pT][pH][pW], scaled by 1/8
    float4 Cv[2][2][2];
#pragma unroll
    for (int ph = 0; ph < 2; ++ph)
#pragma unroll
        for (int pw = 0; pw < 2; ++pw) {
            Cv[0][ph][pw] = scl4(add4(Bv[0][ph][pw], Bv[1][ph][pw]), 0.125f);
            Cv[1][ph][pw] = scl4(sub4(Bv[0][ph][pw], Bv[1][ph][pw]), 0.125f);
        }

    // ---- scatter the 2x2x8 output block (streaming / nontemporal) ----
    // out flat: (((b*G + g)*2T + t)*2H + h)*2W + w, with w base = 8*wq (32B aligned)
    const int TO = 2 * TI, HO = 2 * HI, WO = 2 * WI;
    const long outBase =
        (((long)(b * G + g) * TO + 2 * ti) * HO + 2 * hi) * WO + (long)wq * 8;

#pragma unroll
    for (int pt = 0; pt < 2; ++pt)
#pragma unroll
        for (int ph = 0; ph < 2; ++ph) {
            const float4 lo = Cv[pt][ph][0];  // even w
            const float4 hv = Cv[pt][ph][1];  // odd  w
            float* p = out + outBase + (long)pt * HO * WO + (long)ph * WO;
            nt_store4(p,     lo.x, hv.x, lo.y, hv.y);
            nt_store4(p + 4, lo.z, hv.z, lo.w, hv.w);
        }
}

extern "C" void kernel_launch(void* const* d_in, const int* in_sizes, int n_in,
                              void* d_out, int out_size, void* d_ws, size_t ws_size,
                              hipStream_t stream) {
    const float* in = (const float*)d_in[0];
    float* out = (float*)d_out;

    // threads = B*G*T*H*(W/4) = 2*16*8*128*32 = 1,048,576
    constexpr int kThreads = 2 * 16 * 8 * 128 * 32;
    constexpr int kBlock = 256;
    ihaar3d_kernel<<<kThreads / kBlock, kBlock, 0, stream>>>(in, out);
}

// Round 5
// 238.549 us; speedup vs baseline: 1.1262x; 1.1262x over previous
//
#include <hip/hip_runtime.h>

// Inverse 3D Haar (UnPatcher): in  [B=2, 8*G=128, T=8,  H=128, W=128] f32
//                              out [B=2,   G=16, 2T=16, 2H=256, 2W=256] f32
//
// out[b,g,2ti+pT,2hi+pH,2wi+pW] = (1/8) * sum_s (-1)^(bits(s)·(pT,pH,pW)) *
//                                 in[b, s*16+g, ti, hi, wi]
// where s = 4*tbit + 2*hbit + wbit (reference split order: lll,llh,lhl,...)
// and c^3 from the three synthesis stages times the 1/(2*sqrt(2)) rescale = 1/8.
//
// R4 lesson: nontemporal stores caused 1.7x HBM write amplification
// (227MB vs 134MB ideal) — nt bypasses L2 write-combining, so 16B lane
// stores hit HBM as partial bursts. Plain cached stores let L2 combine
// to full-line writebacks.

__device__ __forceinline__ float4 add4(float4 a, float4 b) {
    return make_float4(a.x + b.x, a.y + b.y, a.z + b.z, a.w + b.w);
}
__device__ __forceinline__ float4 sub4(float4 a, float4 b) {
    return make_float4(a.x - b.x, a.y - b.y, a.z - b.z, a.w - b.w);
}
__device__ __forceinline__ float4 scl4(float4 a, float s) {
    return make_float4(a.x * s, a.y * s, a.z * s, a.w * s);
}

__global__ __launch_bounds__(256) void ihaar3d_kernel(const float* __restrict__ in,
                                                      float* __restrict__ out) {
    constexpr int TI = 8, HI = 128, WI = 128;   // input spatial dims
    constexpr int G  = 16;                      // output channels per batch
    constexpr int WQ = WI / 4;                  // 32 float4 per input W-row

    int idx = blockIdx.x * blockDim.x + threadIdx.x;
    const int wq = idx & (WQ - 1); idx >>= 5;   // float4 index along W_in
    const int hi = idx & (HI - 1); idx >>= 7;
    const int ti = idx & (TI - 1); idx >>= 3;
    const int g  = idx & (G  - 1); idx >>= 4;
    const int b  = idx;                         // 0..1

    // ---- gather the 8 subband float4s (all coalesced) ----
    const long inBase =
        (((long)(b * 128 + g) * TI + ti) * HI + hi) * WI + (long)wq * 4;
    const long sstride = (long)16 * TI * HI * WI;  // 16 channels * spatial

    float4 v[8];
#pragma unroll
    for (int s = 0; s < 8; ++s)
        v[s] = *reinterpret_cast<const float4*>(in + inBase + (long)s * sstride);

    // ---- 3-stage butterfly, all statically indexed (stays in VGPRs) ----
    // Stage W: A[tb][hb][pW]
    float4 A[2][2][2];
#pragma unroll
    for (int tb = 0; tb < 2; ++tb)
#pragma unroll
        for (int hb = 0; hb < 2; ++hb) {
            const float4 lo = v[4 * tb + 2 * hb + 0];
            const float4 hv = v[4 * tb + 2 * hb + 1];
            A[tb][hb][0] = add4(lo, hv);
            A[tb][hb][1] = sub4(lo, hv);
        }
    // Stage H: Bv[tb][pH][pW]
    float4 Bv[2][2][2];
#pragma unroll
    for (int tb = 0; tb < 2; ++tb)
#pragma unroll
        for (int pw = 0; pw < 2; ++pw) {
            Bv[tb][0][pw] = add4(A[tb][0][pw], A[tb][1][pw]);
            Bv[tb][1][pw] = sub4(A[tb][0][pw], A[tb][1][pw]);
        }
    // Stage T: Cv[pT][pH][pW], scaled by 1/8
    float4 Cv[2][2][2];
#pragma unroll
    for (int ph = 0; ph < 2; ++ph)
#pragma unroll
        for (int pw = 0; pw < 2; ++pw) {
            Cv[0][ph][pw] = scl4(add4(Bv[0][ph][pw], Bv[1][ph][pw]), 0.125f);
            Cv[1][ph][pw] = scl4(sub4(Bv[0][ph][pw], Bv[1][ph][pw]), 0.125f);
        }

    // ---- scatter the 2x2x8 output block (plain cached stores) ----
    // out flat: (((b*G + g)*2T + t)*2H + h)*2W + w, with w base = 8*wq (32B aligned)
    const int TO = 2 * TI, HO = 2 * HI, WO = 2 * WI;
    const long outBase =
        (((long)(b * G + g) * TO + 2 * ti) * HO + 2 * hi) * WO + (long)wq * 8;

#pragma unroll
    for (int pt = 0; pt < 2; ++pt)
#pragma unroll
        for (int ph = 0; ph < 2; ++ph) {
            const float4 lo = Cv[pt][ph][0];  // even w
            const float4 hv = Cv[pt][ph][1];  // odd  w
            const float4 o0 = make_float4(lo.x, hv.x, lo.y, hv.y);
            const float4 o1 = make_float4(lo.z, hv.z, lo.w, hv.w);
            float* p = out + outBase + (long)pt * HO * WO + (long)ph * WO;
            *reinterpret_cast<float4*>(p)     = o0;
            *reinterpret_cast<float4*>(p + 4) = o1;
        }
}

extern "C" void kernel_launch(void* const* d_in, const int* in_sizes, int n_in,
                              void* d_out, int out_size, void* d_ws, size_t ws_size,
                              hipStream_t stream) {
    const float* in = (const float*)d_in[0];
    float* out = (float*)d_out;

    // threads = B*G*T*H*(W/4) = 2*16*8*128*32 = 1,048,576
    constexpr int kThreads = 2 * 16 * 8 * 128 * 32;
    constexpr int kBlock = 256;
    ihaar3d_kernel<<<kThreads / kBlock, kBlock, 0, stream>>>(in, out);
}

// Round 6
// 230.644 us; speedup vs baseline: 1.1648x; 1.0343x over previous
//
#include <hip/hip_runtime.h>

// Inverse 3D Haar (UnPatcher): in  [B=2, 8*G=128, T=8,  H=128, W=128] f32
//                              out [B=2,   G=16, 2T=16, 2H=256, 2W=256] f32
//
// out[b,g,2ti+pT,2hi+pH,2wi+pW] = (1/8) * sum_s (-1)^(bits(s)·(pT,pH,pW)) *
//                                 in[b, s*16+g, ti, hi, wi]
// where s = 4*tbit + 2*hbit + wbit (reference split order), and
// c^3 * 1/(2*sqrt(2)) = 1/8 exactly.
//
// R4 lesson: nontemporal stores -> 1.7x HBM write amplification (nt bypasses
//            L2 write-combining). Use plain cached stores.
// R5 lesson: traffic is ideal (131MB W / 66MB F) but 86us vs 43us roofline.
//            Store instructions were 16B-per-lane at 32B stride (50% line
//            contiguity). This round: one thread per input float2, so every
//            store instruction is lane-contiguous (64 x 16B = 1KiB).

__device__ __forceinline__ float2 add2(float2 a, float2 b) {
    return make_float2(a.x + b.x, a.y + b.y);
}
__device__ __forceinline__ float2 sub2(float2 a, float2 b) {
    return make_float2(a.x - b.x, a.y - b.y);
}
__device__ __forceinline__ float2 scl2(float2 a, float s) {
    return make_float2(a.x * s, a.y * s);
}

__global__ __launch_bounds__(256) void ihaar3d_kernel(const float* __restrict__ in,
                                                      float* __restrict__ out) {
    constexpr int TI = 8, HI = 128, WI = 128;   // input spatial dims
    constexpr int G  = 16;                      // output channels per batch
    constexpr int WP = WI / 2;                  // 64 float2 per input W-row

    int idx = blockIdx.x * blockDim.x + threadIdx.x;
    const int wp = idx & (WP - 1); idx >>= 6;   // float2 index along W_in
    const int hi = idx & (HI - 1); idx >>= 7;
    const int ti = idx & (TI - 1); idx >>= 3;
    const int g  = idx & (G  - 1); idx >>= 4;
    const int b  = idx;                         // 0..1

    // ---- gather the 8 subband float2s (8B/lane, coalesced) ----
    const long inBase =
        (((long)(b * 128 + g) * TI + ti) * HI + hi) * WI + (long)wp * 2;
    const long sstride = (long)16 * TI * HI * WI;  // 16 channels * spatial

    float2 v[8];
#pragma unroll
    for (int s = 0; s < 8; ++s)
        v[s] = *reinterpret_cast<const float2*>(in + inBase + (long)s * sstride);

    // ---- 3-stage butterfly on float2 (two consecutive wi), static idx ----
    // Stage W: A[tb][hb][pW] — pW = output w-parity, components = wi0, wi1
    float2 A[2][2][2];
#pragma unroll
    for (int tb = 0; tb < 2; ++tb)
#pragma unroll
        for (int hb = 0; hb < 2; ++hb) {
            const float2 lo = v[4 * tb + 2 * hb + 0];
            const float2 hv = v[4 * tb + 2 * hb + 1];
            A[tb][hb][0] = add2(lo, hv);
            A[tb][hb][1] = sub2(lo, hv);
        }
    // Stage H: Bv[tb][pH][pW]
    float2 Bv[2][2][2];
#pragma unroll
    for (int tb = 0; tb < 2; ++tb)
#pragma unroll
        for (int pw = 0; pw < 2; ++pw) {
            Bv[tb][0][pw] = add2(A[tb][0][pw], A[tb][1][pw]);
            Bv[tb][1][pw] = sub2(A[tb][0][pw], A[tb][1][pw]);
        }
    // Stage T: Cv[pT][pH][pW], scaled by 1/8
    float2 Cv[2][2][2];
#pragma unroll
    for (int ph = 0; ph < 2; ++ph)
#pragma unroll
        for (int pw = 0; pw < 2; ++pw) {
            Cv[0][ph][pw] = scl2(add2(Bv[0][ph][pw], Bv[1][ph][pw]), 0.125f);
            Cv[1][ph][pw] = scl2(sub2(Bv[0][ph][pw], Bv[1][ph][pw]), 0.125f);
        }

    // ---- scatter: 4 fully lane-contiguous float4 stores ----
    // out flat: (((b*G + g)*2T + t)*2H + h)*2W + w, w base = 4*wp (16B aligned;
    // consecutive lanes -> consecutive 16B -> 1KiB contiguous per wave store)
    const int TO = 2 * TI, HO = 2 * HI, WO = 2 * WI;
    const long outBase =
        (((long)(b * G + g) * TO + 2 * ti) * HO + 2 * hi) * WO + (long)wp * 4;

#pragma unroll
    for (int pt = 0; pt < 2; ++pt)
#pragma unroll
        for (int ph = 0; ph < 2; ++ph) {
            const float2 E = Cv[pt][ph][0];  // even-w outputs at (wi0, wi1)
            const float2 O = Cv[pt][ph][1];  // odd-w  outputs at (wi0, wi1)
            float* p = out + outBase + (long)pt * HO * WO + (long)ph * WO;
            *reinterpret_cast<float4*>(p) = make_float4(E.x, O.x, E.y, O.y);
        }
}

extern "C" void kernel_launch(void* const* d_in, const int* in_sizes, int n_in,
                              void* d_out, int out_size, void* d_ws, size_t ws_size,
                              hipStream_t stream) {
    const float* in = (const float*)d_in[0];
    float* out = (float*)d_out;

    // threads = B*G*T*H*(W/2) = 2*16*8*128*64 = 2,097,152
    constexpr int kThreads = 2 * 16 * 8 * 128 * 64;
    constexpr int kBlock = 256;
    ihaar3d_kernel<<<kThreads / kBlock, kBlock, 0, stream>>>(in, out);
}